// Round 2
// baseline (7208.224 us; speedup 1.0000x reference)
//
#include <hip/hip_runtime.h>
#include <hip/hip_cooperative_groups.h>

#define D 768
#define BQ 8
#define TT 256
#define VOC 50257
#define NPAD 50304
#define MROWS 2048
#define NWG 96

typedef __attribute__((ext_vector_type(8))) short short8;
typedef __attribute__((ext_vector_type(4))) float f32x4;

__device__ __forceinline__ void gld_lds16(const void* g, void* l) {
    __builtin_amdgcn_global_load_lds(
        (const __attribute__((address_space(1))) unsigned int*)g,
        (__attribute__((address_space(3))) unsigned int*)l, 16, 0, 0);
}

__device__ __forceinline__ unsigned short f2bf(float x) {
    unsigned u = __builtin_bit_cast(unsigned, x);
    unsigned r = (u + 0x7FFFu + ((u >> 16) & 1u)) >> 16;
    return (unsigned short)r;
}

// ---------------- core_out row inverse norms ----------------
__global__ __launch_bounds__(256) void invn_k(const float* __restrict__ core,
                                              float* __restrict__ invn) {
    int r = blockIdx.x;                 // 0..2047  (= t*8+b)
    const float* x = core + (size_t)r * D;
    int tid = threadIdx.x, lane = tid & 63, wv = tid >> 6;
    __shared__ float lds[4];
    float s = 0.f;
    #pragma unroll
    for (int q = 0; q < 3; ++q) { float v = x[tid + q * 256]; s += v * v; }
    #pragma unroll
    for (int off = 32; off > 0; off >>= 1) s += __shfl_xor(s, off);
    if (lane == 0) lds[wv] = s;
    __syncthreads();
    if (tid == 0) {
        float tot = lds[0] + lds[1] + lds[2] + lds[3];
        invn[r] = 1.0f / fmaxf(sqrtf(tot), 1e-12f);
    }
}

// ---------------- embedding f32 -> bf16 (padded rows zeroed) ----------------
__global__ __launch_bounds__(256) void conv_k(const float* __restrict__ E,
                                              unsigned short* __restrict__ eB) {
    const int total = NPAD * D / 4;     // groups of 4 elems
    const int valid = VOC * D / 4;
    for (int g = blockIdx.x * 256 + threadIdx.x; g < total; g += gridDim.x * 256) {
        unsigned p0, p1;
        if (g < valid) {
            float4 v = *(const float4*)(E + (size_t)g * 4);
            p0 = (unsigned)f2bf(v.x) | ((unsigned)f2bf(v.y) << 16);
            p1 = (unsigned)f2bf(v.z) | ((unsigned)f2bf(v.w) << 16);
        } else { p0 = 0u; p1 = 0u; }
        uint2 o; o.x = p0; o.y = p1;
        *(uint2*)(eB + (size_t)g * 4) = o;
    }
}

// ---------------- sequential scan (cooperative, 1 grid sync / step) ----------------
// wave gw owns R columns j = 2*gw, 2*gw+1; R^T column held in 12 VGPRs per lane.
__global__ __launch_bounds__(256) void scan_k(
    const float* __restrict__ R0,    // [768][768] row-major
    const float* __restrict__ h0,    // [8][768]
    const float* __restrict__ rgam, const float* __restrict__ rbet,
    const float* __restrict__ core,  // [256][8][768] raw core_out
    const float* __restrict__ invn,  // [2048]
    float* __restrict__ ybuf,        // [256][8][768]  y = core_n + 0.1*temporal
    float* __restrict__ P)           // [256][NWG][16] per-WG LN partials
{
    __shared__ float hp[BQ * D];     // 24KB: h_{t-1}
    __shared__ float g_lds[D], be_lds[D];
    __shared__ float red[16];
    __shared__ float wsums[4 * 16];
    const int tid = threadIdx.x, lane = tid & 63, wv = tid >> 6;
    const int gw = blockIdx.x * 4 + wv;          // 0..383

    float rr[2][12];
    #pragma unroll
    for (int c = 0; c < 2; ++c) {
        int j = 2 * gw + c;
        #pragma unroll
        for (int m = 0; m < 12; ++m) {
            int i = 128 * (m >> 1) + 2 * lane + (m & 1);
            rr[c][m] = R0[(size_t)i * D + j];
        }
    }
    for (int e = tid; e < D; e += 256) { g_lds[e] = rgam[e]; be_lds[e] = rbet[e]; }

    cooperative_groups::grid_group grid = cooperative_groups::this_grid();

    for (int t = 0; t < TT; ++t) {
        // ---- rebuild h_{t-1} into LDS ----
        if (t == 0) {
            for (int e = tid; e < BQ * D; e += 256) hp[e] = h0[e];
        } else {
            if (tid < 16) {
                float v = 0.f;
                const float* pp = P + (size_t)(t - 1) * NWG * 16 + tid;
                #pragma unroll 8
                for (int g2 = 0; g2 < NWG; ++g2) v += pp[g2 * 16];
                red[tid] = v;
            }
            __syncthreads();
            float ms[8], rs[8];
            #pragma unroll
            for (int b = 0; b < 8; ++b) {
                float mb = red[2 * b] * (1.0f / 768.0f);
                float vb = red[2 * b + 1] * (1.0f / 768.0f) - mb * mb;
                ms[b] = mb; rs[b] = rsqrtf(vb + 1e-5f);
            }
            const float* yprev = ybuf + (size_t)(t - 1) * BQ * D;
            #pragma unroll
            for (int b = 0; b < 8; ++b)
                for (int e = tid; e < D; e += 256)
                    hp[b * D + e] = (yprev[b * D + e] - ms[b]) * rs[b] * g_lds[e] + be_lds[e];
        }
        __syncthreads();

        float inb[8];
        #pragma unroll
        for (int b = 0; b < 8; ++b) inb[b] = invn[t * 8 + b];
        float cs[8], cq[8];
        #pragma unroll
        for (int b = 0; b < 8; ++b) { cs[b] = 0.f; cq[b] = 0.f; }

        #pragma unroll
        for (int c = 0; c < 2; ++c) {
            int j = 2 * gw + c;
            // pass 1: x_hat column
            float xp[8];
            #pragma unroll
            for (int b = 0; b < 8; ++b) xp[b] = 0.f;
            #pragma unroll
            for (int k = 0; k < 6; ++k) {
                float ra = rr[c][2 * k], rb2 = rr[c][2 * k + 1];
                int i = 128 * k + 2 * lane;
                #pragma unroll
                for (int b = 0; b < 8; ++b) {
                    float2 h2 = *(const float2*)&hp[b * D + i];
                    xp[b] = fmaf(h2.y, rb2, fmaf(h2.x, ra, xp[b]));
                }
            }
            #pragma unroll
            for (int b = 0; b < 8; ++b)
                #pragma unroll
                for (int off = 32; off > 0; off >>= 1) xp[b] += __shfl_xor(xp[b], off);

            float cvv[8], ev[8];
            #pragma unroll
            for (int b = 0; b < 8; ++b) {
                cvv[b] = core[((size_t)t * 8 + b) * D + j] * inb[b];
                ev[b] = cvv[b] - xp[b];
            }
            // pass 2: R update (decay + hebbian + clip) and temporal
            float tp[8];
            #pragma unroll
            for (int b = 0; b < 8; ++b) tp[b] = 0.f;
            #pragma unroll
            for (int k = 0; k < 6; ++k) {
                int i = 128 * k + 2 * lane;
                float d0 = 0.f, d1 = 0.f;
                float2 hh[8];
                #pragma unroll
                for (int b = 0; b < 8; ++b) {
                    hh[b] = *(const float2*)&hp[b * D + i];
                    d0 = fmaf(hh[b].x, ev[b], d0);
                    d1 = fmaf(hh[b].y, ev[b], d1);
                }
                float r0 = fmaf(2.5e-4f, d0, 0.999f * rr[c][2 * k]);
                float r1 = fmaf(2.5e-4f, d1, 0.999f * rr[c][2 * k + 1]);
                r0 = fminf(fmaxf(r0, -3.0f), 3.0f);
                r1 = fminf(fmaxf(r1, -3.0f), 3.0f);
                rr[c][2 * k] = r0; rr[c][2 * k + 1] = r1;
                #pragma unroll
                for (int b = 0; b < 8; ++b) tp[b] = fmaf(hh[b].y, r1, fmaf(hh[b].x, r0, tp[b]));
            }
            #pragma unroll
            for (int b = 0; b < 8; ++b)
                #pragma unroll
                for (int off = 32; off > 0; off >>= 1) tp[b] += __shfl_xor(tp[b], off);

            float yv[8];
            #pragma unroll
            for (int b = 0; b < 8; ++b) {
                yv[b] = cvv[b] + 0.1f * tp[b];
                cs[b] += yv[b]; cq[b] += yv[b] * yv[b];
            }
            if (lane == 0) {
                float* yo = ybuf + (size_t)t * BQ * D + j;
                #pragma unroll
                for (int b = 0; b < 8; ++b) yo[b * D] = yv[b];
            }
        }
        if (lane == 0) {
            #pragma unroll
            for (int b = 0; b < 8; ++b) {
                wsums[wv * 16 + 2 * b] = cs[b];
                wsums[wv * 16 + 2 * b + 1] = cq[b];
            }
        }
        __syncthreads();
        if (tid < 16)
            P[((size_t)t * NWG + blockIdx.x) * 16 + tid] =
                wsums[tid] + wsums[16 + tid] + wsums[32 + tid] + wsums[48 + tid];
        grid.sync();
    }
}

// ---------------- per-row: h=LN1(y), fused=LN2(h + l2norm(E[tok])), to bf16 ----------------
__global__ __launch_bounds__(256) void fused_k(
    const float* __restrict__ ybuf, const float* __restrict__ E,
    const int* __restrict__ tok,
    const float* __restrict__ rg, const float* __restrict__ rbp,
    const float* __restrict__ og, const float* __restrict__ obp,
    unsigned short* __restrict__ fB)
{
    int m = blockIdx.x;                // 0..2047 = t*8+b
    int t = m >> 3, b = m & 7;
    int tid = threadIdx.x, lane = tid & 63, wv = tid >> 6;
    __shared__ float lds[16];
    int token = tok[b * TT + t];
    const float* y = ybuf + (size_t)m * D;
    const float* e = E + (size_t)token * D;
    float yv[3], evv[3];
    float s0 = 0.f, s1 = 0.f, s2 = 0.f;
    #pragma unroll
    for (int q = 0; q < 3; ++q) {
        int idx = tid + q * 256;
        yv[q] = y[idx]; evv[q] = e[idx];
        s0 += yv[q]; s1 += yv[q] * yv[q]; s2 += evv[q] * evv[q];
    }
    #pragma unroll
    for (int off = 32; off > 0; off >>= 1) {
        s0 += __shfl_xor(s0, off); s1 += __shfl_xor(s1, off); s2 += __shfl_xor(s2, off);
    }
    if (lane == 0) { lds[wv * 4 + 0] = s0; lds[wv * 4 + 1] = s1; lds[wv * 4 + 2] = s2; }
    __syncthreads();
    s0 = lds[0] + lds[4] + lds[8] + lds[12];
    s1 = lds[1] + lds[5] + lds[9] + lds[13];
    s2 = lds[2] + lds[6] + lds[10] + lds[14];
    float m1 = s0 * (1.f / 768.f);
    float rs1 = rsqrtf(s1 * (1.f / 768.f) - m1 * m1 + 1e-5f);
    float einv = 1.0f / fmaxf(sqrtf(s2), 1e-12f);
    float zv[3]; float z0 = 0.f, z1 = 0.f;
    #pragma unroll
    for (int q = 0; q < 3; ++q) {
        int idx = tid + q * 256;
        float h = (yv[q] - m1) * rs1 * rg[idx] + rbp[idx];
        float z = h + evv[q] * einv;
        zv[q] = z; z0 += z; z1 += z * z;
    }
    __syncthreads();
    #pragma unroll
    for (int off = 32; off > 0; off >>= 1) { z0 += __shfl_xor(z0, off); z1 += __shfl_xor(z1, off); }
    if (lane == 0) { lds[wv * 4 + 0] = z0; lds[wv * 4 + 1] = z1; }
    __syncthreads();
    z0 = lds[0] + lds[4] + lds[8] + lds[12];
    z1 = lds[1] + lds[5] + lds[9] + lds[13];
    float m2f = z0 * (1.f / 768.f);
    float rs2 = rsqrtf(z1 * (1.f / 768.f) - m2f * m2f + 1e-5f);
    #pragma unroll
    for (int q = 0; q < 3; ++q) {
        int idx = tid + q * 256;
        float f = (zv[q] - m2f) * rs2 * og[idx] + obp[idx];
        fB[(size_t)m * D + idx] = f2bf(f);
    }
}

// ---------------- logits GEMM: [2048,768]bf16 @ [50304,768]bf16^T -> f32 ----------------
__global__ __launch_bounds__(256) void gemm_k(const unsigned short* __restrict__ A,
                                              const unsigned short* __restrict__ Bm,
                                              float* __restrict__ C) {
    __shared__ unsigned short As[128 * 32];   // [row][k] rows of 64B
    __shared__ unsigned short Bs[128 * 32];
    const int tid = threadIdx.x;
    const int lane = tid & 63;
    const int w = tid >> 6;
    const int wr = w >> 1, wc = w & 1;
    const int bid = blockIdx.x;
    const int bm = bid & 15;                  // 2048/128
    const int bn = bid >> 4;                  // 0..392
    const size_t m0 = (size_t)bm * 128;
    const size_t n0 = (size_t)bn * 128;
    const int r16 = lane & 15, kg = lane >> 4;
    f32x4 acc[4][4];
    #pragma unroll
    for (int i = 0; i < 4; ++i)
        #pragma unroll
        for (int j = 0; j < 4; ++j) acc[i][j] = (f32x4){0.f, 0.f, 0.f, 0.f};

    for (int kt = 0; kt < 768; kt += 32) {
        #pragma unroll
        for (int q = 0; q < 2; ++q) {
            int o = (q * 256 + tid) * 16;      // byte offset into 8KB tile
            int row = o >> 6;
            int ce = (o & 63) >> 1;            // element within row
            gld_lds16(A + (m0 + row) * 768 + kt + ce, (char*)As + o);
            gld_lds16(Bm + (n0 + row) * 768 + kt + ce, (char*)Bs + o);
        }
        __syncthreads();
        short8 af[4], bfr[4];
        #pragma unroll
        for (int i = 0; i < 4; ++i)
            af[i] = *(const short8*)((const char*)As + (wr * 64 + i * 16 + r16) * 64 + kg * 16);
        #pragma unroll
        for (int j = 0; j < 4; ++j)
            bfr[j] = *(const short8*)((const char*)Bs + (wc * 64 + j * 16 + r16) * 64 + kg * 16);
        #pragma unroll
        for (int i = 0; i < 4; ++i)
            #pragma unroll
            for (int j = 0; j < 4; ++j)
                acc[i][j] = __builtin_amdgcn_mfma_f32_16x16x32_bf16(af[i], bfr[j], acc[i][j], 0, 0, 0);
        __syncthreads();
    }
    #pragma unroll
    for (int i = 0; i < 4; ++i) {
        int rbase = (int)m0 + wr * 64 + i * 16 + kg * 4;
        #pragma unroll
        for (int j = 0; j < 4; ++j) {
            int col = (int)n0 + wc * 64 + j * 16 + r16;
            if (col < VOC) {
                #pragma unroll
                for (int r = 0; r < 4; ++r)
                    C[(size_t)(rbase + r) * VOC + col] = acc[i][j][r];
            }
        }
    }
}

extern "C" void kernel_launch(void* const* d_in, const int* in_sizes, int n_in,
                              void* d_out, int out_size, void* d_ws, size_t ws_size,
                              hipStream_t stream) {
    const float* E    = (const float*)d_in[0];
    const float* R0   = (const float*)d_in[1];
    const float* h0   = (const float*)d_in[2];
    const float* rg   = (const float*)d_in[3];
    const float* rbp  = (const float*)d_in[4];
    const float* og   = (const float*)d_in[5];
    const float* obp  = (const float*)d_in[6];
    const float* core = (const float*)d_in[7];
    const int*   tok  = (const int*)d_in[8];
    float* C = (float*)d_out;

    char* ws = (char*)d_ws;
    float* ybuf          = (float*)(ws);                    // 6,291,456 B
    float* P             = (float*)(ws + 6291456);          // 1,572,864 B
    float* invn          = (float*)(ws + 7864320);          //     8,192 B
    unsigned short* fB   = (unsigned short*)(ws + 7872512); // 3,145,728 B
    unsigned short* eB   = (unsigned short*)(ws + 11018240);// 77,266,944 B

    hipLaunchKernelGGL(invn_k, dim3(MROWS), dim3(256), 0, stream, core, invn);

    void* sargs[8] = {(void*)&R0, (void*)&h0, (void*)&rg, (void*)&rbp,
                      (void*)&core, (void*)&invn, (void*)&ybuf, (void*)&P};
    hipLaunchCooperativeKernel(scan_k, dim3(NWG), dim3(256), sargs, 0, stream);

    hipLaunchKernelGGL(conv_k, dim3(4096), dim3(256), 0, stream, E, eB);
    hipLaunchKernelGGL(fused_k, dim3(MROWS), dim3(256), 0, stream,
                       ybuf, E, tok, rg, rbp, og, obp, fB);
    hipLaunchKernelGGL(gemm_k, dim3(16 * 393), dim3(256), 0, stream, fB, eB, C);
}